// Round 12
// baseline (115.481 us; speedup 1.0000x reference)
//
#include <hip/hip_runtime.h>
#include <math.h>

#define NROWS 2048
#define DDIM 32
#define SBLK 16               // stats blocks per array
#define SROWS (NROWS / SBLK)  // 128 rows per stats block
#define REPS 3  // diagnostic: dur = base + (REPS-1)*k_core; surfaces main in rocprof

// ---------------------------------------------------------------------------
// Stage 1: coalesced per-column partial sums (identical to r7 champion).
// ---------------------------------------------------------------------------
__global__ __launch_bounds__(256) void HybridKernel_stats_partial(
    const float* __restrict__ x, const float* __restrict__ y,
    float* __restrict__ part) {
  const int b = blockIdx.x;
  const int a = b >> 4;
  const int blk = b & (SBLK - 1);
  const float* in = a ? y : x;
  const int t = threadIdx.x;
  const int col = t & 31;
  const int rg = t >> 5;  // 0..7
  float s = 0.f, s2 = 0.f;
  const int r0 = blk * SROWS + rg;
#pragma unroll
  for (int i = 0; i < SROWS / 8; ++i) {
    float v = in[(r0 + i * 8) * DDIM + col];
    s += v;
    s2 = fmaf(v, v, s2);
  }
  __shared__ float ss[8][32];
  __shared__ float sq[8][32];
  ss[rg][col] = s;
  sq[rg][col] = s2;
  __syncthreads();
  if (t < 32) {
    float S = 0.f, Q = 0.f;
#pragma unroll
    for (int g = 0; g < 8; ++g) {
      S += ss[g][t];
      Q += sq[g][t];
    }
    part[b * 64 + t] = S;
    part[b * 64 + 32 + t] = Q;
  }
}

// ---------------------------------------------------------------------------
// Stage 2: EXACT r7 champion structure; compute core repeated REPS times.
// Per-rep volatile opaque constants (scalar v_mov) defeat inter-rep CSE
// without array/memory asm refs (r8's spill cause). Last rep -> epilogue.
// ---------------------------------------------------------------------------
__global__ __launch_bounds__(512, 2) void HybridKernel_main(
    const float* __restrict__ x, const float* __restrict__ y,
    const float* __restrict__ part, float* __restrict__ out) {
  __shared__ float4 sD[2][24 * 128];
  __shared__ float sNrm[2][128];
  __shared__ float sMu[2][32];
  __shared__ float sInv[2][32];

  const int t = threadIdx.x;
  const int i0 = blockIdx.y * 128;
  const int j0 = blockIdx.x * 128;

  // --- hoist tile global loads (independent of stats) ---
  float4 gx[2], gy[2];
#pragma unroll
  for (int rep = 0; rep < 2; ++rep) {
    const int u = t + 512 * rep;
    const int row = u >> 3;
    const int q = u & 7;
    gx[rep] = *reinterpret_cast<const float4*>(&x[(i0 + row) * DDIM + q * 4]);
    gy[rep] = *reinterpret_cast<const float4*>(&y[(j0 + row) * DDIM + q * 4]);
  }

  // --- finalize stats (mean, 1/(std+eps), ddof=1) from partials ---
  if (t < 64) {
    const int a = t >> 5;
    const int c = t & 31;
    float S = 0.f, Q = 0.f;
#pragma unroll
    for (int bb = 0; bb < SBLK; ++bb) {
      S += part[(a * SBLK + bb) * 64 + c];
      Q += part[(a * SBLK + bb) * 64 + 32 + c];
    }
    const float n = (float)NROWS;
    const float mean = S / n;
    const float var = fmaxf((Q - S * mean) / (n - 1.f), 0.f);
    sMu[a][c] = mean;
    sInv[a][c] = 1.f / (sqrtf(var) + 1e-8f);
  }
  __syncthreads();

  // --- staging: 1024 (row,quad) units per side, 2 reps over 512 threads ---
#pragma unroll
  for (int rep = 0; rep < 2; ++rep) {
    const int u = t + 512 * rep;
    const int row = u >> 3;
    const int q = u & 7;
#pragma unroll
    for (int side = 0; side < 2; ++side) {
      const float4 g = side ? gy[rep] : gx[rep];
      const float sc = side ? 1.0f : 0.5f;
      const float gv[4] = {g.x, g.y, g.z, g.w};
      float xn[4], hc[4], hs[4];
      float nrm = 0.f;
#pragma unroll
      for (int k = 0; k < 4; ++k) {
        const int d = q * 4 + k;
        xn[k] = (gv[k] - sMu[side][d]) * sInv[side][d];
        nrm = fmaf(xn[k], xn[k], nrm);
        float sn, cs;
        __sincosf(gv[k], &sn, &cs);
        hc[k] = sc * cs;
        hs[k] = sc * sn;
      }
      sD[side][(16 + q) * 128 + (row ^ q)] =
          make_float4(xn[0], xn[1], xn[2], xn[3]);
      const int dp0 = 2 * q, dp1 = 2 * q + 1;
      sD[side][dp0 * 128 + (row ^ (dp0 & 7))] =
          make_float4(hc[0], hs[0], hc[1], hs[1]);
      sD[side][dp1 * 128 + (row ^ (dp1 & 7))] =
          make_float4(hc[2], hs[2], hc[3], hs[3]);
      nrm += __shfl_xor(nrm, 1);
      nrm += __shfl_xor(nrm, 2);
      nrm += __shfl_xor(nrm, 4);
      if ((t & 7) == 0) sNrm[side][row] = nrm;
    }
  }
  __syncthreads();

  // --- main compute: r7 core (24 phases, 8x4 per thread), REPS reps ---
  const int tx = t & 31;
  const int ty = t >> 5;
  const float4* sD0 = &sD[0][0];
  const float4* sD1 = &sD[1][0];

  float acc[8][4];
  float qp[8][4];

#pragma unroll 1
  for (int rep3 = 0; rep3 < REPS; ++rep3) {
    // opaque per-rep constants: block inter-rep CSE, zero pressure cost
    float opZero, opHalf, opOne;
    asm volatile("v_mov_b32 %0, 0" : "=v"(opZero));
    asm volatile("v_mov_b32 %0, 0.5" : "=v"(opHalf));
    asm volatile("v_mov_b32 %0, 1.0" : "=v"(opOne));

#pragma unroll
    for (int r = 0; r < 8; ++r)
#pragma unroll
      for (int c = 0; c < 4; ++c) {
        acc[r][c] = opZero;
        qp[r][c] = opOne;
      }

#pragma unroll
    for (int q = 0; q < 8; ++q) {
      // phase C: xn quad (slot 16+q)
      {
        const int S = 16 + q;
        const int sw = S & 7;
        float4 FX[8], FY[4];
#pragma unroll
        for (int i = 0; i < 8; ++i) FX[i] = sD0[S * 128 + ((ty + 16 * i) ^ sw)];
#pragma unroll
        for (int j = 0; j < 4; ++j) FY[j] = sD1[S * 128 + ((tx + 32 * j) ^ sw)];
#pragma unroll
        for (int r = 0; r < 8; ++r)
#pragma unroll
          for (int c = 0; c < 4; ++c) {
            float a = acc[r][c];
            a = fmaf(FX[r].x, FY[c].x, a);
            a = fmaf(FX[r].y, FY[c].y, a);
            a = fmaf(FX[r].z, FY[c].z, a);
            a = fmaf(FX[r].w, FY[c].w, a);
            acc[r][c] = a;
          }
      }
      // phases Q0, Q1: cos/sin pairs (slots 2q, 2q+1)
#pragma unroll
      for (int h = 0; h < 2; ++h) {
        const int S = 2 * q + h;
        const int sw = S & 7;
        float4 FX[8], FY[4];
#pragma unroll
        for (int i = 0; i < 8; ++i) FX[i] = sD0[S * 128 + ((ty + 16 * i) ^ sw)];
#pragma unroll
        for (int j = 0; j < 4; ++j) FY[j] = sD1[S * 128 + ((tx + 32 * j) ^ sw)];
#pragma unroll
        for (int r = 0; r < 8; ++r)
#pragma unroll
          for (int c = 0; c < 4; ++c) {
            const float t0 =
                fmaf(FX[r].x, FY[c].x, fmaf(FX[r].y, FY[c].y, opHalf));
            const float t1 =
                fmaf(FX[r].z, FY[c].z, fmaf(FX[r].w, FY[c].w, opHalf));
            qp[r][c] *= t0 * t1;
          }
      }
    }
  }

  // --- epilogue (uses last rep's values; identical math to r7) ---
  float nx[8], ny[4];
#pragma unroll
  for (int r = 0; r < 8; ++r) nx[r] = sNrm[0][ty + 16 * r];
#pragma unroll
  for (int c = 0; c < 4; ++c) ny[c] = sNrm[1][tx + 32 * c];

#pragma unroll
  for (int r = 0; r < 8; ++r) {
    const int row = i0 + ty + 16 * r;
    float* o = out + (size_t)row * NROWS + j0;
#pragma unroll
    for (int c = 0; c < 4; ++c) {
      const float cl = __expf(2.f * acc[r][c] - nx[r] - ny[c]);
      o[tx + 32 * c] = 0.5f * (cl + qp[r][c]);
    }
  }
}

extern "C" void kernel_launch(void* const* d_in, const int* in_sizes, int n_in,
                              void* d_out, int out_size, void* d_ws,
                              size_t ws_size, hipStream_t stream) {
  const float* x = (const float*)d_in[0];
  const float* y = (const float*)d_in[1];
  float* part = (float*)d_ws;  // 2*SBLK*64 = 2048 floats
  float* out = (float*)d_out;

  HybridKernel_stats_partial<<<2 * SBLK, 256, 0, stream>>>(x, y, part);
  dim3 grid(NROWS / 128, NROWS / 128);
  HybridKernel_main<<<grid, 512, 0, stream>>>(x, y, part, out);
}

// Round 13
// 24.552 us; speedup vs baseline: 4.7036x; 4.7036x over previous
//
#include <hip/hip_runtime.h>
#include <math.h>

#define NROWS 2048
#define DDIM 32
#define SBLK 16               // stats blocks per array
#define SROWS (NROWS / SBLK)  // 128 rows per stats block

typedef __attribute__((ext_vector_type(8))) short short8;  // 8 bf16
typedef __attribute__((ext_vector_type(4))) float f32x4;

// ---------------------------------------------------------------------------
// Stage 1: coalesced per-column partial sums (identical to r7 champion).
// ---------------------------------------------------------------------------
__global__ __launch_bounds__(256) void HybridKernel_stats_partial(
    const float* __restrict__ x, const float* __restrict__ y,
    float* __restrict__ part) {
  const int b = blockIdx.x;
  const int a = b >> 4;
  const int blk = b & (SBLK - 1);
  const float* in = a ? y : x;
  const int t = threadIdx.x;
  const int col = t & 31;
  const int rg = t >> 5;  // 0..7
  float s = 0.f, s2 = 0.f;
  const int r0 = blk * SROWS + rg;
#pragma unroll
  for (int i = 0; i < SROWS / 8; ++i) {
    float v = in[(r0 + i * 8) * DDIM + col];
    s += v;
    s2 = fmaf(v, v, s2);
  }
  __shared__ float ss[8][32];
  __shared__ float sq[8][32];
  ss[rg][col] = s;
  sq[rg][col] = s2;
  __syncthreads();
  if (t < 32) {
    float S = 0.f, Q = 0.f;
#pragma unroll
    for (int g = 0; g < 8; ++g) {
      S += ss[g][t];
      Q += sq[g][t];
    }
    part[b * 64 + t] = S;
    part[b * 64 + 32 + t] = Q;
  }
}

__device__ __forceinline__ unsigned packbf(float a, float b) {
  // bf16(a) in low 16, bf16(b) in high 16 (truncation; lo-plane captures rest)
  return (__float_as_uint(a) >> 16) | (__float_as_uint(b) & 0xffff0000u);
}

// ---------------------------------------------------------------------------
// Stage 2: 128x128 tile per 512-thread block (8 waves, 2/SIMD).
// Classical via MFMA (bf16 hi/lo split, 3 passes, exact to ~1e-6):
//   wave w owns rows [32*(w>>1),+32) x cols [64*(w&1),+64) = 2x4 16x16 tiles.
//   xn staged as bf16 hi/lo planes, row-major 80B stride (conflict-free
//   b128 frag reads); A-frag: lane l -> row (l&15), k = 8*(l>>4)+i.
// Quantum on VALU in the MFMA C/D layout (col=lane&15, row=4*(lane>>4)+reg):
//   16 phases (cos/sin d-pairs), 12 ds_read_b128 each, XOR-swizzled slots.
// classical = exp(2*dot - nx - ny); quantum term = 0.5 + hcx*cy + hsx*sy.
// ---------------------------------------------------------------------------
__global__ __launch_bounds__(512, 2) void HybridKernel_main(
    const float* __restrict__ x, const float* __restrict__ y,
    const float* __restrict__ part, float* __restrict__ out) {
  __shared__ float4 sCS[2][16 * 128];    // 64 KB swizzled cos/sin pairs
  __shared__ uint4 sXB[2][2][128 * 5];   // 40 KB bf16 [side][hi/lo], 80B/row
  __shared__ float sNrm[2][128];
  __shared__ float sMu[2][32];
  __shared__ float sInv[2][32];

  const int t = threadIdx.x;
  const int i0 = blockIdx.y * 128;
  const int j0 = blockIdx.x * 128;

  // --- hoist tile global loads (independent of stats) ---
  float4 gx[2], gy[2];
#pragma unroll
  for (int rep = 0; rep < 2; ++rep) {
    const int u = t + 512 * rep;
    const int row = u >> 3;
    const int q = u & 7;
    gx[rep] = *reinterpret_cast<const float4*>(&x[(i0 + row) * DDIM + q * 4]);
    gy[rep] = *reinterpret_cast<const float4*>(&y[(j0 + row) * DDIM + q * 4]);
  }

  // --- finalize stats (mean, 1/(std+eps), ddof=1) from partials ---
  if (t < 64) {
    const int a = t >> 5;
    const int c = t & 31;
    float S = 0.f, Q = 0.f;
#pragma unroll
    for (int bb = 0; bb < SBLK; ++bb) {
      S += part[(a * SBLK + bb) * 64 + c];
      Q += part[(a * SBLK + bb) * 64 + 32 + c];
    }
    const float n = (float)NROWS;
    const float mean = S / n;
    const float var = fmaxf((Q - S * mean) / (n - 1.f), 0.f);
    sMu[a][c] = mean;
    sInv[a][c] = 1.f / (sqrtf(var) + 1e-8f);
  }
  __syncthreads();

  // --- staging ---
#pragma unroll
  for (int rep = 0; rep < 2; ++rep) {
    const int u = t + 512 * rep;
    const int row = u >> 3;
    const int q = u & 7;
#pragma unroll
    for (int side = 0; side < 2; ++side) {
      const float4 g = side ? gy[rep] : gx[rep];
      const float sc = side ? 1.0f : 0.5f;
      const float gv[4] = {g.x, g.y, g.z, g.w};
      float xn[4], hc[4], hs[4];
      float nrm = 0.f;
#pragma unroll
      for (int k = 0; k < 4; ++k) {
        const int d = q * 4 + k;
        xn[k] = (gv[k] - sMu[side][d]) * sInv[side][d];
        nrm = fmaf(xn[k], xn[k], nrm);
        float sn, cs;
        __sincosf(gv[k], &sn, &cs);
        hc[k] = sc * cs;
        hs[k] = sc * sn;
      }
      // cos/sin slots (2 d's per float4), XOR-swizzled
      const int dp0 = 2 * q, dp1 = 2 * q + 1;
      sCS[side][dp0 * 128 + (row ^ (dp0 & 7))] =
          make_float4(hc[0], hs[0], hc[1], hs[1]);
      sCS[side][dp1 * 128 + (row ^ (dp1 & 7))] =
          make_float4(hc[2], hs[2], hc[3], hs[3]);
      // bf16 hi/lo planes, 80B row stride
      float hif[4], lof[4];
#pragma unroll
      for (int k = 0; k < 4; ++k) {
        hif[k] = __uint_as_float(__float_as_uint(xn[k]) & 0xffff0000u);
        lof[k] = xn[k] - hif[k];
      }
      char* bh = (char*)&sXB[side][0][0] + row * 80 + q * 8;
      char* bl = (char*)&sXB[side][1][0] + row * 80 + q * 8;
      *reinterpret_cast<uint2*>(bh) =
          make_uint2(packbf(hif[0], hif[1]), packbf(hif[2], hif[3]));
      *reinterpret_cast<uint2*>(bl) =
          make_uint2(packbf(lof[0], lof[1]), packbf(lof[2], lof[3]));
      // row norm
      nrm += __shfl_xor(nrm, 1);
      nrm += __shfl_xor(nrm, 2);
      nrm += __shfl_xor(nrm, 4);
      if ((t & 7) == 0) sNrm[side][row] = nrm;
    }
  }
  __syncthreads();

  // --- wave/lane geometry (MFMA C/D layout) ---
  const int w = t >> 6;
  const int l = t & 63;
  const int l4 = l >> 4;  // 0..3
  const int ln = l & 15;
  const int R0 = (w >> 1) * 32;  // wave row base
  const int C0 = (w & 1) * 64;   // wave col base

  // --- classical via MFMA: 2x4 tiles, hi/lo 3-pass ---
  short8 Ah[2], Al[2], Bh[4], Bl[4];
  {
    const char* bxh = (const char*)&sXB[0][0][0];
    const char* bxl = (const char*)&sXB[0][1][0];
    const char* byh = (const char*)&sXB[1][0][0];
    const char* byl = (const char*)&sXB[1][1][0];
#pragma unroll
    for (int tr = 0; tr < 2; ++tr) {
      const int off = (R0 + 16 * tr + ln) * 80 + l4 * 16;
      Ah[tr] = *reinterpret_cast<const short8*>(bxh + off);
      Al[tr] = *reinterpret_cast<const short8*>(bxl + off);
    }
#pragma unroll
    for (int tc = 0; tc < 4; ++tc) {
      const int off = (C0 + 16 * tc + ln) * 80 + l4 * 16;
      Bh[tc] = *reinterpret_cast<const short8*>(byh + off);
      Bl[tc] = *reinterpret_cast<const short8*>(byl + off);
    }
  }
  f32x4 dotacc[2][4];
#pragma unroll
  for (int tr = 0; tr < 2; ++tr)
#pragma unroll
    for (int tc = 0; tc < 4; ++tc) {
      f32x4 a = {0.f, 0.f, 0.f, 0.f};
      a = __builtin_amdgcn_mfma_f32_16x16x32_bf16(Ah[tr], Bl[tc], a, 0, 0, 0);
      a = __builtin_amdgcn_mfma_f32_16x16x32_bf16(Al[tr], Bh[tc], a, 0, 0, 0);
      a = __builtin_amdgcn_mfma_f32_16x16x32_bf16(Ah[tr], Bh[tc], a, 0, 0, 0);
      dotacc[tr][tc] = a;
    }

  // --- classical epilogue: exp(2*dot - nx - ny), in MFMA layout ---
  int r_idx[8], c_idx[4];
#pragma unroll
  for (int ri = 0; ri < 8; ++ri)
    r_idx[ri] = R0 + 16 * (ri >> 2) + 4 * l4 + (ri & 3);
#pragma unroll
  for (int tc = 0; tc < 4; ++tc) c_idx[tc] = C0 + 16 * tc + ln;

  float cl[8][4];
#pragma unroll
  for (int tr = 0; tr < 2; ++tr) {
#pragma unroll
    for (int mm = 0; mm < 4; ++mm) {
      const float nx = sNrm[0][r_idx[tr * 4 + mm]];
#pragma unroll
      for (int tc = 0; tc < 4; ++tc) {
        const float ny = sNrm[1][c_idx[tc]];
        cl[tr * 4 + mm][tc] =
            __expf(2.f * dotacc[tr][tc][mm] - nx - ny);
      }
    }
  }

  // --- quantum: 16 phases on VALU, same (row,col) ownership ---
  const float4* sCS0 = &sCS[0][0];
  const float4* sCS1 = &sCS[1][0];
  float qp[8][4];
#pragma unroll
  for (int ri = 0; ri < 8; ++ri)
#pragma unroll
    for (int tc = 0; tc < 4; ++tc) qp[ri][tc] = 1.f;

#pragma unroll
  for (int dp = 0; dp < 16; ++dp) {
    const int sw = dp & 7;
    float4 FX[8], FY[4];
#pragma unroll
    for (int ri = 0; ri < 8; ++ri)
      FX[ri] = sCS0[dp * 128 + (r_idx[ri] ^ sw)];
#pragma unroll
    for (int tc = 0; tc < 4; ++tc)
      FY[tc] = sCS1[dp * 128 + (c_idx[tc] ^ sw)];
#pragma unroll
    for (int ri = 0; ri < 8; ++ri)
#pragma unroll
      for (int tc = 0; tc < 4; ++tc) {
        const float t0 =
            fmaf(FX[ri].x, FY[tc].x, fmaf(FX[ri].y, FY[tc].y, 0.5f));
        const float t1 =
            fmaf(FX[ri].z, FY[tc].z, fmaf(FX[ri].w, FY[tc].w, 0.5f));
        qp[ri][tc] *= t0 * t1;
      }
  }

  // --- combine + store ---
#pragma unroll
  for (int ri = 0; ri < 8; ++ri) {
    float* o = out + (size_t)(i0 + r_idx[ri]) * NROWS + j0;
#pragma unroll
    for (int tc = 0; tc < 4; ++tc) {
      o[c_idx[tc]] = 0.5f * (cl[ri][tc] + qp[ri][tc]);
    }
  }
}

extern "C" void kernel_launch(void* const* d_in, const int* in_sizes, int n_in,
                              void* d_out, int out_size, void* d_ws,
                              size_t ws_size, hipStream_t stream) {
  const float* x = (const float*)d_in[0];
  const float* y = (const float*)d_in[1];
  float* part = (float*)d_ws;  // 2*SBLK*64 = 2048 floats
  float* out = (float*)d_out;

  HybridKernel_stats_partial<<<2 * SBLK, 256, 0, stream>>>(x, y, part);
  dim3 grid(NROWS / 128, NROWS / 128);
  HybridKernel_main<<<grid, 512, 0, stream>>>(x, y, part, out);
}

// Round 14
// 24.261 us; speedup vs baseline: 4.7600x; 1.0120x over previous
//
#include <hip/hip_runtime.h>
#include <math.h>

#define NROWS 2048
#define DDIM 32

typedef __attribute__((ext_vector_type(8))) short short8;  // 8 bf16
typedef __attribute__((ext_vector_type(4))) float f32x4;

__device__ __forceinline__ unsigned packbf(float a, float b) {
  // bf16(a) in low 16, bf16(b) in high 16 (truncation; lo-plane captures rest)
  return (__float_as_uint(a) >> 16) | (__float_as_uint(b) & 0xffff0000u);
}

// ---------------------------------------------------------------------------
// Single fused kernel. 128x128 tile per 512-thread block (8 waves, 2/SIMD).
// Prologue: tile loads -> cs staging (raw x, no stats needed) -> redundant
//   per-block full-input stats (512 KB L2-resident streaming, hidden under
//   staging) -> bf16 hi/lo staging + row norms.
// Classical via MFMA (bf16 hi/lo 3-pass, ~1e-6 exact); quantum on VALU in
// MFMA C/D layout (col=lane&15, row=4*(lane>>4)+reg), 16 phases of 12
// XOR-swizzled ds_read_b128.
// classical = exp(2*dot - nx - ny); quantum term = 0.5 + hcx*cy + hsx*sy.
// ---------------------------------------------------------------------------
__global__ __launch_bounds__(512, 2) void HybridKernel_fused(
    const float* __restrict__ x, const float* __restrict__ y,
    float* __restrict__ out) {
  __shared__ float4 sCS[2][16 * 128];   // 64 KB swizzled cos/sin pairs
  __shared__ uint4 sXB[2][2][128 * 5];  // 40 KB bf16 [side][hi/lo], 80B/row
  __shared__ float4 sRed[2][64][8];     // 16 KB stats partials (sum)
  __shared__ float4 sRedQ[2][64][8];    // 16 KB stats partials (sumsq)
  __shared__ float sNrm[2][128];
  __shared__ float sMu[2][32];
  __shared__ float sInv[2][32];

  const int t = threadIdx.x;
  const int i0 = blockIdx.y * 128;
  const int j0 = blockIdx.x * 128;

  // --- 1. hoist tile global loads ---
  float4 gx[2], gy[2];
#pragma unroll
  for (int rep = 0; rep < 2; ++rep) {
    const int u = t + 512 * rep;
    const int row = u >> 3;
    const int q = u & 7;
    gx[rep] = *reinterpret_cast<const float4*>(&x[(i0 + row) * DDIM + q * 4]);
    gy[rep] = *reinterpret_cast<const float4*>(&y[(j0 + row) * DDIM + q * 4]);
  }

  // --- 2. cs staging (needs only raw values, overlaps stats reads below) ---
#pragma unroll
  for (int rep = 0; rep < 2; ++rep) {
    const int u = t + 512 * rep;
    const int row = u >> 3;
    const int q = u & 7;
#pragma unroll
    for (int side = 0; side < 2; ++side) {
      const float4 g = side ? gy[rep] : gx[rep];
      const float sc = side ? 1.0f : 0.5f;
      const float gv[4] = {g.x, g.y, g.z, g.w};
      float hc[4], hs[4];
#pragma unroll
      for (int k = 0; k < 4; ++k) {
        float sn, cs;
        __sincosf(gv[k], &sn, &cs);
        hc[k] = sc * cs;
        hs[k] = sc * sn;
      }
      const int dp0 = 2 * q, dp1 = 2 * q + 1;
      sCS[side][dp0 * 128 + (row ^ (dp0 & 7))] =
          make_float4(hc[0], hs[0], hc[1], hs[1]);
      sCS[side][dp1 * 128 + (row ^ (dp1 & 7))] =
          make_float4(hc[2], hs[2], hc[3], hs[3]);
    }
  }

  // --- 3. stats streaming: thread covers colquad cq, rows rg+64*i ---
  {
    const int cq = t & 7;
    const int rg = t >> 3;  // 0..63
    const float4* px = reinterpret_cast<const float4*>(x) + rg * 8 + cq;
    const float4* py = reinterpret_cast<const float4*>(y) + rg * 8 + cq;
    float4 sx = {0.f, 0.f, 0.f, 0.f}, qx = {0.f, 0.f, 0.f, 0.f};
    float4 sy = {0.f, 0.f, 0.f, 0.f}, qy = {0.f, 0.f, 0.f, 0.f};
#pragma unroll 4
    for (int i = 0; i < NROWS / 64; ++i) {  // 32 iters
      const float4 vx = px[(size_t)i * 64 * 8];
      const float4 vy = py[(size_t)i * 64 * 8];
      sx.x += vx.x; qx.x = fmaf(vx.x, vx.x, qx.x);
      sx.y += vx.y; qx.y = fmaf(vx.y, vx.y, qx.y);
      sx.z += vx.z; qx.z = fmaf(vx.z, vx.z, qx.z);
      sx.w += vx.w; qx.w = fmaf(vx.w, vx.w, qx.w);
      sy.x += vy.x; qy.x = fmaf(vy.x, vy.x, qy.x);
      sy.y += vy.y; qy.y = fmaf(vy.y, vy.y, qy.y);
      sy.z += vy.z; qy.z = fmaf(vy.z, vy.z, qy.z);
      sy.w += vy.w; qy.w = fmaf(vy.w, vy.w, qy.w);
    }
    sRed[0][rg][cq] = sx;
    sRedQ[0][rg][cq] = qx;
    sRed[1][rg][cq] = sy;
    sRedQ[1][rg][cq] = qy;
  }
  __syncthreads();
  // two-stage reduce: 128 threads sum 8 rowgroups each -> [2][8][8]
  if (t < 128) {
    const int a = t >> 6;
    const int g8 = (t >> 3) & 7;  // which group-of-8
    const int cq = t & 7;
    float4 S = {0.f, 0.f, 0.f, 0.f}, Q = {0.f, 0.f, 0.f, 0.f};
#pragma unroll
    for (int k = 0; k < 8; ++k) {
      const float4 a1 = sRed[a][g8 * 8 + k][cq];
      const float4 b1 = sRedQ[a][g8 * 8 + k][cq];
      S.x += a1.x; S.y += a1.y; S.z += a1.z; S.w += a1.w;
      Q.x += b1.x; Q.y += b1.y; Q.z += b1.z; Q.w += b1.w;
    }
    sRed[a][g8][cq] = S;
    sRedQ[a][g8][cq] = Q;
  }
  __syncthreads();
  if (t < 16) {  // t = a*8 + cq
    const int a = t >> 3;
    const int cq = t & 7;
    float4 S = {0.f, 0.f, 0.f, 0.f}, Q = {0.f, 0.f, 0.f, 0.f};
#pragma unroll
    for (int k = 0; k < 8; ++k) {
      const float4 a1 = sRed[a][k][cq];
      const float4 b1 = sRedQ[a][k][cq];
      S.x += a1.x; S.y += a1.y; S.z += a1.z; S.w += a1.w;
      Q.x += b1.x; Q.y += b1.y; Q.z += b1.z; Q.w += b1.w;
    }
    const float Sa[4] = {S.x, S.y, S.z, S.w};
    const float Qa[4] = {Q.x, Q.y, Q.z, Q.w};
    const float n = (float)NROWS;
#pragma unroll
    for (int k = 0; k < 4; ++k) {
      const float mean = Sa[k] / n;
      const float var = fmaxf((Qa[k] - Sa[k] * mean) / (n - 1.f), 0.f);
      sMu[a][cq * 4 + k] = mean;
      sInv[a][cq * 4 + k] = 1.f / (sqrtf(var) + 1e-8f);
    }
  }
  __syncthreads();

  // --- 4. bf16 hi/lo staging + row norms (needs stats) ---
#pragma unroll
  for (int rep = 0; rep < 2; ++rep) {
    const int u = t + 512 * rep;
    const int row = u >> 3;
    const int q = u & 7;
#pragma unroll
    for (int side = 0; side < 2; ++side) {
      const float4 g = side ? gy[rep] : gx[rep];
      const float gv[4] = {g.x, g.y, g.z, g.w};
      float xn[4];
      float nrm = 0.f;
#pragma unroll
      for (int k = 0; k < 4; ++k) {
        const int d = q * 4 + k;
        xn[k] = (gv[k] - sMu[side][d]) * sInv[side][d];
        nrm = fmaf(xn[k], xn[k], nrm);
      }
      float hif[4], lof[4];
#pragma unroll
      for (int k = 0; k < 4; ++k) {
        hif[k] = __uint_as_float(__float_as_uint(xn[k]) & 0xffff0000u);
        lof[k] = xn[k] - hif[k];
      }
      char* bh = (char*)&sXB[side][0][0] + row * 80 + q * 8;
      char* bl = (char*)&sXB[side][1][0] + row * 80 + q * 8;
      *reinterpret_cast<uint2*>(bh) =
          make_uint2(packbf(hif[0], hif[1]), packbf(hif[2], hif[3]));
      *reinterpret_cast<uint2*>(bl) =
          make_uint2(packbf(lof[0], lof[1]), packbf(lof[2], lof[3]));
      nrm += __shfl_xor(nrm, 1);
      nrm += __shfl_xor(nrm, 2);
      nrm += __shfl_xor(nrm, 4);
      if ((t & 7) == 0) sNrm[side][row] = nrm;
    }
  }
  __syncthreads();

  // --- wave/lane geometry (MFMA C/D layout) ---
  const int w = t >> 6;
  const int l = t & 63;
  const int l4 = l >> 4;  // 0..3
  const int ln = l & 15;
  const int R0 = (w >> 1) * 32;  // wave row base
  const int C0 = (w & 1) * 64;   // wave col base

  // --- classical via MFMA: 2x4 tiles, hi/lo 3-pass ---
  short8 Ah[2], Al[2], Bh[4], Bl[4];
  {
    const char* bxh = (const char*)&sXB[0][0][0];
    const char* bxl = (const char*)&sXB[0][1][0];
    const char* byh = (const char*)&sXB[1][0][0];
    const char* byl = (const char*)&sXB[1][1][0];
#pragma unroll
    for (int tr = 0; tr < 2; ++tr) {
      const int off = (R0 + 16 * tr + ln) * 80 + l4 * 16;
      Ah[tr] = *reinterpret_cast<const short8*>(bxh + off);
      Al[tr] = *reinterpret_cast<const short8*>(bxl + off);
    }
#pragma unroll
    for (int tc = 0; tc < 4; ++tc) {
      const int off = (C0 + 16 * tc + ln) * 80 + l4 * 16;
      Bh[tc] = *reinterpret_cast<const short8*>(byh + off);
      Bl[tc] = *reinterpret_cast<const short8*>(byl + off);
    }
  }
  f32x4 dotacc[2][4];
#pragma unroll
  for (int tr = 0; tr < 2; ++tr)
#pragma unroll
    for (int tc = 0; tc < 4; ++tc) {
      f32x4 a = {0.f, 0.f, 0.f, 0.f};
      a = __builtin_amdgcn_mfma_f32_16x16x32_bf16(Ah[tr], Bl[tc], a, 0, 0, 0);
      a = __builtin_amdgcn_mfma_f32_16x16x32_bf16(Al[tr], Bh[tc], a, 0, 0, 0);
      a = __builtin_amdgcn_mfma_f32_16x16x32_bf16(Ah[tr], Bh[tc], a, 0, 0, 0);
      dotacc[tr][tc] = a;
    }

  // --- classical epilogue: exp(2*dot - nx - ny), in MFMA layout ---
  int r_idx[8], c_idx[4];
#pragma unroll
  for (int ri = 0; ri < 8; ++ri)
    r_idx[ri] = R0 + 16 * (ri >> 2) + 4 * l4 + (ri & 3);
#pragma unroll
  for (int tc = 0; tc < 4; ++tc) c_idx[tc] = C0 + 16 * tc + ln;

  float cl[8][4];
#pragma unroll
  for (int tr = 0; tr < 2; ++tr) {
#pragma unroll
    for (int mm = 0; mm < 4; ++mm) {
      const float nx = sNrm[0][r_idx[tr * 4 + mm]];
#pragma unroll
      for (int tc = 0; tc < 4; ++tc) {
        const float ny = sNrm[1][c_idx[tc]];
        cl[tr * 4 + mm][tc] = __expf(2.f * dotacc[tr][tc][mm] - nx - ny);
      }
    }
  }

  // --- quantum: 16 phases on VALU, same (row,col) ownership ---
  const float4* sCS0 = &sCS[0][0];
  const float4* sCS1 = &sCS[1][0];
  float qp[8][4];
#pragma unroll
  for (int ri = 0; ri < 8; ++ri)
#pragma unroll
    for (int tc = 0; tc < 4; ++tc) qp[ri][tc] = 1.f;

#pragma unroll
  for (int dp = 0; dp < 16; ++dp) {
    const int sw = dp & 7;
    float4 FX[8], FY[4];
#pragma unroll
    for (int ri = 0; ri < 8; ++ri) FX[ri] = sCS0[dp * 128 + (r_idx[ri] ^ sw)];
#pragma unroll
    for (int tc = 0; tc < 4; ++tc) FY[tc] = sCS1[dp * 128 + (c_idx[tc] ^ sw)];
#pragma unroll
    for (int ri = 0; ri < 8; ++ri)
#pragma unroll
      for (int tc = 0; tc < 4; ++tc) {
        const float t0 =
            fmaf(FX[ri].x, FY[tc].x, fmaf(FX[ri].y, FY[tc].y, 0.5f));
        const float t1 =
            fmaf(FX[ri].z, FY[tc].z, fmaf(FX[ri].w, FY[tc].w, 0.5f));
        qp[ri][tc] *= t0 * t1;
      }
  }

  // --- combine + store ---
#pragma unroll
  for (int ri = 0; ri < 8; ++ri) {
    float* o = out + (size_t)(i0 + r_idx[ri]) * NROWS + j0;
#pragma unroll
    for (int tc = 0; tc < 4; ++tc) {
      o[c_idx[tc]] = 0.5f * (cl[ri][tc] + qp[ri][tc]);
    }
  }
}

extern "C" void kernel_launch(void* const* d_in, const int* in_sizes, int n_in,
                              void* d_out, int out_size, void* d_ws,
                              size_t ws_size, hipStream_t stream) {
  const float* x = (const float*)d_in[0];
  const float* y = (const float*)d_in[1];
  float* out = (float*)d_out;

  dim3 grid(NROWS / 128, NROWS / 128);
  HybridKernel_fused<<<grid, 512, 0, stream>>>(x, y, out);
}